// Round 2
// baseline (1146.045 us; speedup 1.0000x reference)
//
#include <hip/hip_runtime.h>
#include <hip/hip_bf16.h>
#include <stdint.h>

#define DD 4096

typedef float v4f __attribute__((ext_vector_type(4)));
typedef short v8s __attribute__((ext_vector_type(8)));

__device__ __forceinline__ unsigned short f2bf(float f){
  union { float f; uint32_t u; } v; v.f = f;
  uint32_t u = v.u;
  uint32_t r = (u + 0x7fffu + ((u >> 16) & 1u)) >> 16;
  return (unsigned short)r;
}
__device__ __forceinline__ ushort4 cvt4(float4 v){
  ushort4 o; o.x = f2bf(v.x); o.y = f2bf(v.y); o.z = f2bf(v.z); o.w = f2bf(v.w); return o;
}
__device__ __forceinline__ float dot4(float4 a, float4 b){
  return a.x*b.x + a.y*b.y + a.z*b.z + a.w*b.w;
}
__device__ __forceinline__ float wred(float v){
  #pragma unroll
  for (int m = 32; m >= 1; m >>= 1) v += __shfl_xor(v, m, 64);
  return v;
}
__device__ __forceinline__ void gload16(const void* g, void* l){
  __builtin_amdgcn_global_load_lds((const __attribute__((address_space(1))) void*)g,
                                   (__attribute__((address_space(3))) void*)l, 16, 0, 0);
}

// ---------------- fp32 -> bf16 convert ----------------
__global__ __launch_bounds__(256) void k_convert_bf16(const float* __restrict__ src,
                                                      unsigned short* __restrict__ dst, int n4){
  int i = blockIdx.x * 256 + threadIdx.x;
  if (i < n4){
    float4 v = ((const float4*)src)[i];
    ((ushort4*)dst)[i] = cvt4(v);
  }
}

// ---------------- cL[k]=dot(ln_w,Wd[k]); cB[k]=dot(ln_b,Wd[k]) ----------------
__global__ __launch_bounds__(256) void k_cwd(const float* __restrict__ lnw,
    const float* __restrict__ lnb, const float* __restrict__ wd,
    float* __restrict__ cL, float* __restrict__ cB)
{
  const int tid = threadIdx.x;
  float aL[8], aB[8];
  #pragma unroll
  for (int k = 0; k < 8; ++k){ aL[k] = 0.f; aB[k] = 0.f; }
  for (int i = tid; i < 1024; i += 256){
    float4 w4 = ((const float4*)lnw)[i];
    float4 b4 = ((const float4*)lnb)[i];
    #pragma unroll
    for (int k = 0; k < 8; ++k){
      float4 d4 = ((const float4*)wd)[(size_t)k*1024 + i];
      aL[k] += dot4(w4, d4);
      aB[k] += dot4(b4, d4);
    }
  }
  __shared__ float sp[4][16];
  const int w = tid >> 6, lane = tid & 63;
  #pragma unroll
  for (int k = 0; k < 8; ++k){
    float v = wred(aL[k]); if (lane == 0) sp[w][k] = v;
    v = wred(aB[k]);       if (lane == 0) sp[w][8+k] = v;
  }
  __syncthreads();
  if (tid < 8)       cL[tid]   = sp[0][tid] + sp[1][tid] + sp[2][tid] + sp[3][tid];
  else if (tid < 16) cB[tid-8] = sp[0][tid] + sp[1][tid] + sp[2][tid] + sp[3][tid];
}

// ---------------- per-row fused pass ----------------
__global__ __launch_bounds__(256) void k_rows(const float* __restrict__ x,
    const float* __restrict__ Am, const float* __restrict__ lnw,
    const float* __restrict__ wd, const float* __restrict__ cL,
    const float* __restrict__ cB, float* __restrict__ t_ws,
    float* __restrict__ bk_ws, unsigned short* __restrict__ xbf, int writeBf)
{
  const int row0 = blockIdx.x * 4;
  const int tid = threadIdx.x;
  float sum[4] = {0,0,0,0}, ssq[4] = {0,0,0,0};
  float dA[4][16], dW[4][8];
  #pragma unroll
  for (int rr = 0; rr < 4; ++rr){
    #pragma unroll
    for (int r = 0; r < 16; ++r) dA[rr][r] = 0.f;
    #pragma unroll
    for (int k = 0; k < 8; ++k)  dW[rr][k] = 0.f;
  }
  #pragma unroll
  for (int i = 0; i < 4; ++i){
    const int d4 = tid + 256*i;
    float4 w4 = ((const float4*)lnw)[d4];
    float4 xv[4];
    #pragma unroll
    for (int rr = 0; rr < 4; ++rr){
      xv[rr] = ((const float4*)x)[(size_t)(row0+rr)*1024 + d4];
      sum[rr] += xv[rr].x + xv[rr].y + xv[rr].z + xv[rr].w;
      ssq[rr] += dot4(xv[rr], xv[rr]);
      if (writeBf) ((ushort4*)xbf)[(size_t)(row0+rr)*1024 + d4] = cvt4(xv[rr]);
    }
    #pragma unroll
    for (int r = 0; r < 16; ++r){
      float4 a4 = ((const float4*)Am)[(size_t)r*1024 + d4];
      #pragma unroll
      for (int rr = 0; rr < 4; ++rr) dA[rr][r] += dot4(xv[rr], a4);
    }
    #pragma unroll
    for (int k = 0; k < 8; ++k){
      float4 wk = ((const float4*)wd)[(size_t)k*1024 + d4];
      float4 lw; lw.x = w4.x*wk.x; lw.y = w4.y*wk.y; lw.z = w4.z*wk.z; lw.w = w4.w*wk.w;
      #pragma unroll
      for (int rr = 0; rr < 4; ++rr) dW[rr][k] += dot4(xv[rr], lw);
    }
  }
  __shared__ float sp[4][104];
  __shared__ float st[104];
  const int w = tid >> 6, lane = tid & 63;
  #pragma unroll
  for (int rr = 0; rr < 4; ++rr){
    float v;
    v = wred(sum[rr]); if (lane == 0) sp[w][rr*26 + 0] = v;
    v = wred(ssq[rr]); if (lane == 0) sp[w][rr*26 + 1] = v;
    #pragma unroll
    for (int r = 0; r < 16; ++r){ v = wred(dA[rr][r]); if (lane == 0) sp[w][rr*26 + 2 + r] = v; }
    #pragma unroll
    for (int k = 0; k < 8; ++k){  v = wred(dW[rr][k]); if (lane == 0) sp[w][rr*26 + 18 + k] = v; }
  }
  __syncthreads();
  if (tid < 104) st[tid] = sp[0][tid] + sp[1][tid] + sp[2][tid] + sp[3][tid];
  __syncthreads();
  if (tid < 64){
    const int rr = tid >> 4, r = tid & 15;
    t_ws[(size_t)(row0+rr)*16 + r] = st[rr*26 + 2 + r];
  } else if (tid < 96){
    const int q = tid - 64; const int rr = q >> 3, k = q & 7;
    const float s  = st[rr*26 + 0];
    const float s2 = st[rr*26 + 1];
    const float mu = s * (1.f/4096.f);
    const float var = s2 * (1.f/4096.f) - mu*mu;
    const float istd = rsqrtf(var + 1e-5f);
    const float raw = istd*st[rr*26 + 18 + k] - mu*istd*cL[k] + cB[k];
    bk_ws[(size_t)(row0+rr)*8 + k] = raw / (1.f + expf(-raw));   // silu
  }
}

// ---------------- shared epilogue ----------------
__device__ __forceinline__ void epilogue(const v4f acc[4][4], const float* bbase,
    const float* t_ws, const float* bk_ws, const float* Bl, const float* Wu,
    float alpha, float* out, int rowBase, int colBase, int wr, int wc, int l)
{
  const int lhi = l >> 4, llo = l & 15;
  #pragma unroll
  for (int nc = 0; nc < 2; ++nc){
    float4 cb4[2][4]; float4 wu4[2][2]; float bbv[2];
    #pragma unroll
    for (int nn = 0; nn < 2; ++nn){
      const int n = nc*2 + nn;
      const int col = colBase + wc*64 + n*16 + llo;
      const float4* pB = (const float4*)(Bl + (size_t)col*16);
      cb4[nn][0] = pB[0]; cb4[nn][1] = pB[1]; cb4[nn][2] = pB[2]; cb4[nn][3] = pB[3];
      const float4* pW = (const float4*)(Wu + (size_t)col*8);
      wu4[nn][0] = pW[0]; wu4[nn][1] = pW[1];
      bbv[nn] = bbase[col];
    }
    #pragma unroll
    for (int m = 0; m < 4; ++m){
      #pragma unroll
      for (int j = 0; j < 4; ++j){
        const int rl = rowBase + wr*64 + m*16 + lhi*4 + j;
        const float4* pT = (const float4*)(t_ws + (size_t)rl*16);
        float4 t0 = pT[0], t1 = pT[1], t2 = pT[2], t3 = pT[3];
        const float4* pK = (const float4*)(bk_ws + (size_t)rl*8);
        float4 b0 = pK[0], b1 = pK[1];
        #pragma unroll
        for (int nn = 0; nn < 2; ++nn){
          const int n = nc*2 + nn;
          float lo = dot4(t0, cb4[nn][0]) + dot4(t1, cb4[nn][1])
                   + dot4(t2, cb4[nn][2]) + dot4(t3, cb4[nn][3]);
          float g  = dot4(b0, wu4[nn][0]) + dot4(b1, wu4[nn][1]);
          float val = acc[m][n][j] + bbv[nn] + (1.f + alpha*tanhf(g)) * (2.f*lo);
          out[(size_t)rl*DD + (size_t)(colBase + wc*64 + n*16 + llo)] = val;
        }
      }
    }
  }
}

// ---------------- tier A: both operands pre-converted bf16, 2-phase prefetch ----------------
__global__ __launch_bounds__(256, 2) void k_gemm_pre(
    const unsigned short* __restrict__ Abf, const unsigned short* __restrict__ Bbf,
    const float* __restrict__ bbase, const float* __restrict__ t_ws,
    const float* __restrict__ bk_ws, const float* __restrict__ Bl,
    const float* __restrict__ Wu, const float* __restrict__ alphap,
    float* __restrict__ out)
{
  __shared__ unsigned short sA[2][128*32];
  __shared__ unsigned short sB[2][128*32];
  const int tid = threadIdx.x;
  const int l = tid & 63;
  const int w = __builtin_amdgcn_readfirstlane(tid >> 6);
  const int wr = w >> 1, wc = w & 1;
  const int rowBase = blockIdx.y * 128;
  const int colBase = blockIdx.x * 128;

  v4f acc[4][4];
  const v4f z4 = {0.f, 0.f, 0.f, 0.f};
  #pragma unroll
  for (int m = 0; m < 4; ++m)
    #pragma unroll
    for (int n = 0; n < 4; ++n) acc[m][n] = z4;

  const unsigned short* gA0 = Abf + (size_t)(rowBase + w*32 + (l>>2))*DD + (l&3)*8;
  const unsigned short* gB0 = Bbf + (size_t)(colBase + w*32 + (l>>2))*DD + (l&3)*8;

  unsigned short* dA0 = &sA[0][(w*32     )*32];
  unsigned short* dA1 = &sA[0][(w*32 + 16)*32];
  unsigned short* dB0 = &sB[0][(w*32     )*32];
  unsigned short* dB1 = &sB[0][(w*32 + 16)*32];

  const unsigned short* pa = &sA[0][(wr*64 + (l&15))*32 + (l>>4)*8];
  const unsigned short* pb = &sB[0][(wc*64 + (l&15))*32 + (l>>4)*8];

  // prologue: stage tile 0 into buffer 0
  {
    gload16(gA0,                 dA0);
    gload16(gA0 + (size_t)16*DD, dA1);
    gload16(gB0,                 dB0);
    gload16(gB0 + (size_t)16*DD, dB1);
  }
  asm volatile("s_waitcnt vmcnt(0)" ::: "memory");
  __builtin_amdgcn_s_barrier();

  int cur = 0;
  for (int kt = 0; kt < 128; ++kt){
    // issue next tile's loads into the other buffer (overlaps ds_read+MFMA)
    if (kt + 1 < 128){
      const int nb = (cur ^ 1) * 4096;
      const size_t go = (size_t)(kt + 1) * 32;
      gload16(gA0 + go,                 dA0 + nb);
      gload16(gA0 + go + (size_t)16*DD, dA1 + nb);
      gload16(gB0 + go,                 dB0 + nb);
      gload16(gB0 + go + (size_t)16*DD, dB1 + nb);
    }
    const int cb = cur * 4096;
    v8s af[4], bfv[4];
    #pragma unroll
    for (int m = 0; m < 4; ++m) af[m]  = *(const v8s*)(pa + cb + m*512);
    #pragma unroll
    for (int n = 0; n < 4; ++n) bfv[n] = *(const v8s*)(pb + cb + n*512);
    #pragma unroll
    for (int m = 0; m < 4; ++m)
      #pragma unroll
      for (int n = 0; n < 4; ++n)
        acc[m][n] = __builtin_amdgcn_mfma_f32_16x16x32_bf16(af[m], bfv[n], acc[m][n], 0, 0, 0);
    asm volatile("s_waitcnt vmcnt(0)" ::: "memory");
    __builtin_amdgcn_s_barrier();
    asm volatile("" ::: "memory");
    cur ^= 1;
  }

  epilogue(acc, bbase, t_ws, bk_ws, Bl, Wu, alphap[0], out, rowBase, colBase, wr, wc, l);
}

// ---------------- tier B: A reg-staged from fp32 x, B pre-converted bf16 ----------------
__global__ __launch_bounds__(256, 2) void k_gemm_wonly(
    const float* __restrict__ Af, const unsigned short* __restrict__ Bbf,
    const float* __restrict__ bbase, const float* __restrict__ t_ws,
    const float* __restrict__ bk_ws, const float* __restrict__ Bl,
    const float* __restrict__ Wu, const float* __restrict__ alphap,
    float* __restrict__ out)
{
  __shared__ unsigned short sA[128*32];
  __shared__ unsigned short sB[128*32];
  const int tid = threadIdx.x;
  const int l = tid & 63;
  const int w = __builtin_amdgcn_readfirstlane(tid >> 6);
  const int wr = w >> 1, wc = w & 1;
  const int rowBase = blockIdx.y * 128;
  const int colBase = blockIdx.x * 128;

  v4f acc[4][4];
  const v4f z4 = {0.f, 0.f, 0.f, 0.f};
  #pragma unroll
  for (int m = 0; m < 4; ++m)
    #pragma unroll
    for (int n = 0; n < 4; ++n) acc[m][n] = z4;

  const unsigned short* gB0 = Bbf + (size_t)(colBase + w*32 + (l>>2))*DD + (l&3)*8;
  unsigned short* dB0 = &sB[(w*32     )*32];
  unsigned short* dB1 = &sB[(w*32 + 16)*32];

  const unsigned short* pa = &sA[(wr*64 + (l&15))*32 + (l>>4)*8];
  const unsigned short* pb = &sB[(wc*64 + (l&15))*32 + (l>>4)*8];

  for (int kt = 0; kt < 128; ++kt){
    gload16(gB0 + (size_t)kt*32,                 dB0);
    gload16(gB0 + (size_t)kt*32 + (size_t)16*DD, dB1);
    #pragma unroll
    for (int q = 0; q < 4; ++q){
      const int f = tid + 256*q;
      const int row = f >> 3, kp = f & 7;
      float4 va = ((const float4*)Af)[(size_t)(rowBase+row)*1024 + kt*8 + kp];
      *(ushort4*)&sA[row*32 + kp*4] = cvt4(va);
    }
    __syncthreads();
    v8s af[4], bfv[4];
    #pragma unroll
    for (int m = 0; m < 4; ++m) af[m]  = *(const v8s*)(pa + m*512);
    #pragma unroll
    for (int n = 0; n < 4; ++n) bfv[n] = *(const v8s*)(pb + n*512);
    #pragma unroll
    for (int m = 0; m < 4; ++m)
      #pragma unroll
      for (int n = 0; n < 4; ++n)
        acc[m][n] = __builtin_amdgcn_mfma_f32_16x16x32_bf16(af[m], bfv[n], acc[m][n], 0, 0, 0);
    __syncthreads();
  }

  epilogue(acc, bbase, t_ws, bk_ws, Bl, Wu, alphap[0], out, rowBase, colBase, wr, wc, l);
}

// ---------------- tier C: both reg-staged from fp32 ----------------
__global__ __launch_bounds__(256, 2) void k_gemm_none(
    const float* __restrict__ Af, const float* __restrict__ Bf,
    const float* __restrict__ bbase, const float* __restrict__ t_ws,
    const float* __restrict__ bk_ws, const float* __restrict__ Bl,
    const float* __restrict__ Wu, const float* __restrict__ alphap,
    float* __restrict__ out)
{
  __shared__ unsigned short sA[128*32];
  __shared__ unsigned short sB[128*32];
  const int tid = threadIdx.x;
  const int l = tid & 63;
  const int w = __builtin_amdgcn_readfirstlane(tid >> 6);
  const int wr = w >> 1, wc = w & 1;
  const int rowBase = blockIdx.y * 128;
  const int colBase = blockIdx.x * 128;

  v4f acc[4][4];
  const v4f z4 = {0.f, 0.f, 0.f, 0.f};
  #pragma unroll
  for (int m = 0; m < 4; ++m)
    #pragma unroll
    for (int n = 0; n < 4; ++n) acc[m][n] = z4;

  const unsigned short* pa = &sA[(wr*64 + (l&15))*32 + (l>>4)*8];
  const unsigned short* pb = &sB[(wc*64 + (l&15))*32 + (l>>4)*8];

  for (int kt = 0; kt < 128; ++kt){
    #pragma unroll
    for (int q = 0; q < 4; ++q){
      const int f = tid + 256*q;
      const int row = f >> 3, kp = f & 7;
      float4 va = ((const float4*)Af)[(size_t)(rowBase+row)*1024 + kt*8 + kp];
      *(ushort4*)&sA[row*32 + kp*4] = cvt4(va);
      float4 vb = ((const float4*)Bf)[(size_t)(colBase+row)*1024 + kt*8 + kp];
      *(ushort4*)&sB[row*32 + kp*4] = cvt4(vb);
    }
    __syncthreads();
    v8s af[4], bfv[4];
    #pragma unroll
    for (int m = 0; m < 4; ++m) af[m]  = *(const v8s*)(pa + m*512);
    #pragma unroll
    for (int n = 0; n < 4; ++n) bfv[n] = *(const v8s*)(pb + n*512);
    #pragma unroll
    for (int m = 0; m < 4; ++m)
      #pragma unroll
      for (int n = 0; n < 4; ++n)
        acc[m][n] = __builtin_amdgcn_mfma_f32_16x16x32_bf16(af[m], bfv[n], acc[m][n], 0, 0, 0);
    __syncthreads();
  }

  epilogue(acc, bbase, t_ws, bk_ws, Bl, Wu, alphap[0], out, rowBase, colBase, wr, wc, l);
}

extern "C" void kernel_launch(void* const* d_in, const int* in_sizes, int n_in,
                              void* d_out, int out_size, void* d_ws, size_t ws_size,
                              hipStream_t stream)
{
  const float* x   = (const float*)d_in[0];
  const float* Wb  = (const float*)d_in[1];
  const float* bb  = (const float*)d_in[2];
  const float* Am  = (const float*)d_in[3];
  const float* Bl  = (const float*)d_in[4];
  const float* lnw = (const float*)d_in[5];
  const float* lnb = (const float*)d_in[6];
  const float* Wd  = (const float*)d_in[7];
  const float* Wu  = (const float*)d_in[8];
  const float* al  = (const float*)d_in[9];
  float* out = (float*)d_out;

  char* ws = (char*)d_ws;
  float* t_ws  = (float*)ws;                       // 512 KiB
  float* bk_ws = (float*)(ws + 524288);            // 256 KiB
  float* cL    = (float*)(ws + 786432);
  float* cB    = (float*)(ws + 786432 + 64);
  const size_t SMALL = 1ull << 20;
  unsigned short* wbf = (unsigned short*)(ws + SMALL);                  // 32 MiB
  unsigned short* xbf = (unsigned short*)(ws + SMALL + (32ull << 20));  // 64 MiB

  const bool haveW = ws_size >= SMALL + (32ull << 20);
  const bool haveX = ws_size >= SMALL + (96ull << 20);

  k_cwd<<<1, 256, 0, stream>>>(lnw, lnb, Wd, cL, cB);
  k_rows<<<2048, 256, 0, stream>>>(x, Am, lnw, Wd, cL, cB, t_ws, bk_ws, xbf, haveX ? 1 : 0);
  if (haveW) k_convert_bf16<<<16384, 256, 0, stream>>>(Wb, wbf, 4194304);

  dim3 gg(32, 64);
  if (haveX)      k_gemm_pre  <<<gg, 256, 0, stream>>>(xbf, wbf, bb, t_ws, bk_ws, Bl, Wu, al, out);
  else if (haveW) k_gemm_wonly<<<gg, 256, 0, stream>>>(x,   wbf, bb, t_ws, bk_ws, Bl, Wu, al, out);
  else            k_gemm_none <<<gg, 256, 0, stream>>>(x,   Wb,  bb, t_ws, bk_ws, Bl, Wu, al, out);
}

// Round 3
// 818.692 us; speedup vs baseline: 1.3998x; 1.3998x over previous
//
#include <hip/hip_runtime.h>
#include <hip/hip_bf16.h>
#include <stdint.h>

#define DD 4096

typedef float v4f __attribute__((ext_vector_type(4)));
typedef short v8s __attribute__((ext_vector_type(8)));

__device__ __forceinline__ unsigned short f2bf(float f){
  union { float f; uint32_t u; } v; v.f = f;
  uint32_t u = v.u;
  uint32_t r = (u + 0x7fffu + ((u >> 16) & 1u)) >> 16;
  return (unsigned short)r;
}
__device__ __forceinline__ ushort4 cvt4(float4 v){
  ushort4 o; o.x = f2bf(v.x); o.y = f2bf(v.y); o.z = f2bf(v.z); o.w = f2bf(v.w); return o;
}
__device__ __forceinline__ float dot4(float4 a, float4 b){
  return a.x*b.x + a.y*b.y + a.z*b.z + a.w*b.w;
}
__device__ __forceinline__ float wred(float v){
  #pragma unroll
  for (int m = 32; m >= 1; m >>= 1) v += __shfl_xor(v, m, 64);
  return v;
}
__device__ __forceinline__ void gload16(const void* g, void* l){
  __builtin_amdgcn_global_load_lds((const __attribute__((address_space(1))) void*)g,
                                   (__attribute__((address_space(3))) void*)l, 16, 0, 0);
}

// ---------------- fp32 -> bf16 convert ----------------
__global__ __launch_bounds__(256) void k_convert_bf16(const float* __restrict__ src,
                                                      unsigned short* __restrict__ dst, int n4){
  int i = blockIdx.x * 256 + threadIdx.x;
  if (i < n4){
    float4 v = ((const float4*)src)[i];
    ((ushort4*)dst)[i] = cvt4(v);
  }
}

// ---------------- cL[k]=dot(ln_w,Wd[k]); cB[k]=dot(ln_b,Wd[k]) ----------------
__global__ __launch_bounds__(256) void k_cwd(const float* __restrict__ lnw,
    const float* __restrict__ lnb, const float* __restrict__ wd,
    float* __restrict__ cL, float* __restrict__ cB)
{
  const int tid = threadIdx.x;
  float aL[8], aB[8];
  #pragma unroll
  for (int k = 0; k < 8; ++k){ aL[k] = 0.f; aB[k] = 0.f; }
  for (int i = tid; i < 1024; i += 256){
    float4 w4 = ((const float4*)lnw)[i];
    float4 b4 = ((const float4*)lnb)[i];
    #pragma unroll
    for (int k = 0; k < 8; ++k){
      float4 d4 = ((const float4*)wd)[(size_t)k*1024 + i];
      aL[k] += dot4(w4, d4);
      aB[k] += dot4(b4, d4);
    }
  }
  __shared__ float sp[4][16];
  const int w = tid >> 6, lane = tid & 63;
  #pragma unroll
  for (int k = 0; k < 8; ++k){
    float v = wred(aL[k]); if (lane == 0) sp[w][k] = v;
    v = wred(aB[k]);       if (lane == 0) sp[w][8+k] = v;
  }
  __syncthreads();
  if (tid < 8)       cL[tid]   = sp[0][tid] + sp[1][tid] + sp[2][tid] + sp[3][tid];
  else if (tid < 16) cB[tid-8] = sp[0][tid] + sp[1][tid] + sp[2][tid] + sp[3][tid];
}

// ---------------- per-row fused pass ----------------
__global__ __launch_bounds__(256) void k_rows(const float* __restrict__ x,
    const float* __restrict__ Am, const float* __restrict__ lnw,
    const float* __restrict__ wd, const float* __restrict__ cL,
    const float* __restrict__ cB, float* __restrict__ t_ws,
    float* __restrict__ bk_ws, unsigned short* __restrict__ xbf, int writeBf)
{
  const int row0 = blockIdx.x * 4;
  const int tid = threadIdx.x;
  float sum[4] = {0,0,0,0}, ssq[4] = {0,0,0,0};
  float dA[4][16], dW[4][8];
  #pragma unroll
  for (int rr = 0; rr < 4; ++rr){
    #pragma unroll
    for (int r = 0; r < 16; ++r) dA[rr][r] = 0.f;
    #pragma unroll
    for (int k = 0; k < 8; ++k)  dW[rr][k] = 0.f;
  }
  #pragma unroll
  for (int i = 0; i < 4; ++i){
    const int d4 = tid + 256*i;
    float4 w4 = ((const float4*)lnw)[d4];
    float4 xv[4];
    #pragma unroll
    for (int rr = 0; rr < 4; ++rr){
      xv[rr] = ((const float4*)x)[(size_t)(row0+rr)*1024 + d4];
      sum[rr] += xv[rr].x + xv[rr].y + xv[rr].z + xv[rr].w;
      ssq[rr] += dot4(xv[rr], xv[rr]);
      if (writeBf) ((ushort4*)xbf)[(size_t)(row0+rr)*1024 + d4] = cvt4(xv[rr]);
    }
    #pragma unroll
    for (int r = 0; r < 16; ++r){
      float4 a4 = ((const float4*)Am)[(size_t)r*1024 + d4];
      #pragma unroll
      for (int rr = 0; rr < 4; ++rr) dA[rr][r] += dot4(xv[rr], a4);
    }
    #pragma unroll
    for (int k = 0; k < 8; ++k){
      float4 wk = ((const float4*)wd)[(size_t)k*1024 + d4];
      float4 lw; lw.x = w4.x*wk.x; lw.y = w4.y*wk.y; lw.z = w4.z*wk.z; lw.w = w4.w*wk.w;
      #pragma unroll
      for (int rr = 0; rr < 4; ++rr) dW[rr][k] += dot4(xv[rr], lw);
    }
  }
  __shared__ float sp[4][104];
  __shared__ float st[104];
  const int w = tid >> 6, lane = tid & 63;
  #pragma unroll
  for (int rr = 0; rr < 4; ++rr){
    float v;
    v = wred(sum[rr]); if (lane == 0) sp[w][rr*26 + 0] = v;
    v = wred(ssq[rr]); if (lane == 0) sp[w][rr*26 + 1] = v;
    #pragma unroll
    for (int r = 0; r < 16; ++r){ v = wred(dA[rr][r]); if (lane == 0) sp[w][rr*26 + 2 + r] = v; }
    #pragma unroll
    for (int k = 0; k < 8; ++k){  v = wred(dW[rr][k]); if (lane == 0) sp[w][rr*26 + 18 + k] = v; }
  }
  __syncthreads();
  if (tid < 104) st[tid] = sp[0][tid] + sp[1][tid] + sp[2][tid] + sp[3][tid];
  __syncthreads();
  if (tid < 64){
    const int rr = tid >> 4, r = tid & 15;
    t_ws[(size_t)(row0+rr)*16 + r] = st[rr*26 + 2 + r];
  } else if (tid < 96){
    const int q = tid - 64; const int rr = q >> 3, k = q & 7;
    const float s  = st[rr*26 + 0];
    const float s2 = st[rr*26 + 1];
    const float mu = s * (1.f/4096.f);
    const float var = s2 * (1.f/4096.f) - mu*mu;
    const float istd = rsqrtf(var + 1e-5f);
    const float raw = istd*st[rr*26 + 18 + k] - mu*istd*cL[k] + cB[k];
    bk_ws[(size_t)(row0+rr)*8 + k] = raw / (1.f + expf(-raw));   // silu
  }
}

// ---------------- shared epilogue ----------------
__device__ __forceinline__ void epilogue(const v4f acc[4][4], const float* bbase,
    const float* t_ws, const float* bk_ws, const float* Bl, const float* Wu,
    float alpha, float* out, int rowBase, int colBase, int wr, int wc, int l)
{
  const int lhi = l >> 4, llo = l & 15;
  #pragma unroll
  for (int nc = 0; nc < 2; ++nc){
    float4 cb4[2][4]; float4 wu4[2][2]; float bbv[2];
    #pragma unroll
    for (int nn = 0; nn < 2; ++nn){
      const int n = nc*2 + nn;
      const int col = colBase + wc*64 + n*16 + llo;
      const float4* pB = (const float4*)(Bl + (size_t)col*16);
      cb4[nn][0] = pB[0]; cb4[nn][1] = pB[1]; cb4[nn][2] = pB[2]; cb4[nn][3] = pB[3];
      const float4* pW = (const float4*)(Wu + (size_t)col*8);
      wu4[nn][0] = pW[0]; wu4[nn][1] = pW[1];
      bbv[nn] = bbase[col];
    }
    #pragma unroll
    for (int m = 0; m < 4; ++m){
      #pragma unroll
      for (int j = 0; j < 4; ++j){
        const int rl = rowBase + wr*64 + m*16 + lhi*4 + j;
        const float4* pT = (const float4*)(t_ws + (size_t)rl*16);
        float4 t0 = pT[0], t1 = pT[1], t2 = pT[2], t3 = pT[3];
        const float4* pK = (const float4*)(bk_ws + (size_t)rl*8);
        float4 b0 = pK[0], b1 = pK[1];
        #pragma unroll
        for (int nn = 0; nn < 2; ++nn){
          const int n = nc*2 + nn;
          float lo = dot4(t0, cb4[nn][0]) + dot4(t1, cb4[nn][1])
                   + dot4(t2, cb4[nn][2]) + dot4(t3, cb4[nn][3]);
          float g  = dot4(b0, wu4[nn][0]) + dot4(b1, wu4[nn][1]);
          float val = acc[m][n][j] + bbv[nn] + (1.f + alpha*tanhf(g)) * (2.f*lo);
          out[(size_t)rl*DD + (size_t)(colBase + wc*64 + n*16 + llo)] = val;
        }
      }
    }
  }
}

// ---------------- tier A: bf16 operands, triple-buffer counted-vmcnt pipeline ----------------
// LDS layout per buffer: A[128][32] bf16 (4096 shorts) then B[128][32] (4096 shorts).
// Bank-conflict swizzle: chunk kc of row r lives at slot kc ^ ((r>>1)&3)  (16B slots).
__global__ __launch_bounds__(256) void k_gemm_pre(
    const unsigned short* __restrict__ Abf, const unsigned short* __restrict__ Bbf,
    const float* __restrict__ bbase, const float* __restrict__ t_ws,
    const float* __restrict__ bk_ws, const float* __restrict__ Bl,
    const float* __restrict__ Wu, const float* __restrict__ alphap,
    float* __restrict__ out)
{
  __shared__ unsigned short smem[3 * 8192];   // 48 KiB
  const int tid = threadIdx.x;
  const int l = tid & 63;
  const int w = __builtin_amdgcn_readfirstlane(tid >> 6);
  const int wr = w >> 1, wc = w & 1;

  // XCD-aware chunked swizzle: 2048 blocks, 8 XCDs, 256 contiguous per XCD.
  const int bid = blockIdx.x;
  const int swz = (bid & 7) * 256 + (bid >> 3);
  const int rowBase = (swz >> 5) * 128;   // 64 row-panels
  const int colBase = (swz & 31) * 128;   // 32 col-panels

  v4f acc[4][4];
  const v4f z4 = {0.f, 0.f, 0.f, 0.f};
  #pragma unroll
  for (int m = 0; m < 4; ++m)
    #pragma unroll
    for (int n = 0; n < 4; ++n) acc[m][n] = z4;

  // staging: lane l covers row (w*32 + (l>>2)) [+16 for second load],
  // global 16B chunk permuted so linear LDS write lands swizzled.
  const int kperm = (l & 3) ^ ((l >> 3) & 3);
  const unsigned short* gA0 = Abf + (size_t)(rowBase + w*32 + (l>>2))*DD + kperm*8;
  const unsigned short* gB0 = Bbf + (size_t)(colBase + w*32 + (l>>2))*DD + kperm*8;

  unsigned short* a0 = &smem[w*1024];          // wave-uniform LDS bases
  unsigned short* b0 = &smem[4096 + w*1024];

  // fragment read pointers with matching XOR slot select
  const int sx = (l >> 4) ^ ((l >> 1) & 3);
  const unsigned short* pa = &smem[(wr*64 + (l&15))*32 + sx*8];
  const unsigned short* pb = &smem[4096 + (wc*64 + (l&15))*32 + sx*8];

#define ISSUE(b, kt) { const size_t go = (size_t)(kt)*32;                          \
    gload16(gA0 + go,                 a0 + (b)*8192);                              \
    gload16(gA0 + go + (size_t)16*DD, a0 + (b)*8192 + 512);                        \
    gload16(gB0 + go,                 b0 + (b)*8192);                              \
    gload16(gB0 + go + (size_t)16*DD, b0 + (b)*8192 + 512); }

#define COMPUTE(b) {                                                               \
    v8s af_[4], bf_[4];                                                            \
    _Pragma("unroll")                                                              \
    for (int m = 0; m < 4; ++m) af_[m] = *(const v8s*)(pa + (b)*8192 + m*512);     \
    _Pragma("unroll")                                                              \
    for (int n = 0; n < 4; ++n) bf_[n] = *(const v8s*)(pb + (b)*8192 + n*512);     \
    _Pragma("unroll")                                                              \
    for (int m = 0; m < 4; ++m)                                                    \
      _Pragma("unroll")                                                            \
      for (int n = 0; n < 4; ++n)                                                  \
        acc[m][n] = __builtin_amdgcn_mfma_f32_16x16x32_bf16(af_[m], bf_[n], acc[m][n], 0, 0, 0); }

  // prologue: tiles 0,1 in flight
  ISSUE(0, 0);
  ISSUE(1, 1);

  for (int t = 0; t < 126; t += 3){
    ISSUE(2, t+2);
    asm volatile("s_waitcnt vmcnt(8)" ::: "memory");
    __builtin_amdgcn_s_barrier();
    COMPUTE(0);
    __builtin_amdgcn_s_barrier();

    ISSUE(0, t+3);
    asm volatile("s_waitcnt vmcnt(8)" ::: "memory");
    __builtin_amdgcn_s_barrier();
    COMPUTE(1);
    __builtin_amdgcn_s_barrier();

    ISSUE(1, t+4);
    asm volatile("s_waitcnt vmcnt(8)" ::: "memory");
    __builtin_amdgcn_s_barrier();
    COMPUTE(2);
    __builtin_amdgcn_s_barrier();
  }
  // peel tiles 126 (buf0), 127 (buf1)
  asm volatile("s_waitcnt vmcnt(4)" ::: "memory");
  __builtin_amdgcn_s_barrier();
  COMPUTE(0);
  asm volatile("s_waitcnt vmcnt(0)" ::: "memory");
  __builtin_amdgcn_s_barrier();
  COMPUTE(1);

#undef ISSUE
#undef COMPUTE

  epilogue(acc, bbase, t_ws, bk_ws, Bl, Wu, alphap[0], out, rowBase, colBase, wr, wc, l);
}

// ---------------- tier C fallback: both reg-staged from fp32 ----------------
__global__ __launch_bounds__(256) void k_gemm_none(
    const float* __restrict__ Af, const float* __restrict__ Bf,
    const float* __restrict__ bbase, const float* __restrict__ t_ws,
    const float* __restrict__ bk_ws, const float* __restrict__ Bl,
    const float* __restrict__ Wu, const float* __restrict__ alphap,
    float* __restrict__ out)
{
  __shared__ unsigned short sA[128*32];
  __shared__ unsigned short sB[128*32];
  const int tid = threadIdx.x;
  const int l = tid & 63;
  const int w = __builtin_amdgcn_readfirstlane(tid >> 6);
  const int wr = w >> 1, wc = w & 1;
  const int rowBase = blockIdx.y * 128;
  const int colBase = blockIdx.x * 128;

  v4f acc[4][4];
  const v4f z4 = {0.f, 0.f, 0.f, 0.f};
  #pragma unroll
  for (int m = 0; m < 4; ++m)
    #pragma unroll
    for (int n = 0; n < 4; ++n) acc[m][n] = z4;

  const unsigned short* pa = &sA[(wr*64 + (l&15))*32 + (l>>4)*8];
  const unsigned short* pb = &sB[(wc*64 + (l&15))*32 + (l>>4)*8];

  for (int kt = 0; kt < 128; ++kt){
    #pragma unroll
    for (int q = 0; q < 4; ++q){
      const int f = tid + 256*q;
      const int row = f >> 3, kp = f & 7;
      float4 va = ((const float4*)Af)[(size_t)(rowBase+row)*1024 + kt*8 + kp];
      *(ushort4*)&sA[row*32 + kp*4] = cvt4(va);
      float4 vb = ((const float4*)Bf)[(size_t)(colBase+row)*1024 + kt*8 + kp];
      *(ushort4*)&sB[row*32 + kp*4] = cvt4(vb);
    }
    __syncthreads();
    v8s af[4], bfv[4];
    #pragma unroll
    for (int m = 0; m < 4; ++m) af[m]  = *(const v8s*)(pa + m*512);
    #pragma unroll
    for (int n = 0; n < 4; ++n) bfv[n] = *(const v8s*)(pb + n*512);
    #pragma unroll
    for (int m = 0; m < 4; ++m)
      #pragma unroll
      for (int n = 0; n < 4; ++n)
        acc[m][n] = __builtin_amdgcn_mfma_f32_16x16x32_bf16(af[m], bfv[n], acc[m][n], 0, 0, 0);
    __syncthreads();
  }

  epilogue(acc, bbase, t_ws, bk_ws, Bl, Wu, alphap[0], out, rowBase, colBase, wr, wc, l);
}

extern "C" void kernel_launch(void* const* d_in, const int* in_sizes, int n_in,
                              void* d_out, int out_size, void* d_ws, size_t ws_size,
                              hipStream_t stream)
{
  const float* x   = (const float*)d_in[0];
  const float* Wb  = (const float*)d_in[1];
  const float* bb  = (const float*)d_in[2];
  const float* Am  = (const float*)d_in[3];
  const float* Bl  = (const float*)d_in[4];
  const float* lnw = (const float*)d_in[5];
  const float* lnb = (const float*)d_in[6];
  const float* Wd  = (const float*)d_in[7];
  const float* Wu  = (const float*)d_in[8];
  const float* al  = (const float*)d_in[9];
  float* out = (float*)d_out;

  char* ws = (char*)d_ws;
  float* t_ws  = (float*)ws;                       // 512 KiB
  float* bk_ws = (float*)(ws + 524288);            // 256 KiB
  float* cL    = (float*)(ws + 786432);
  float* cB    = (float*)(ws + 786432 + 64);
  const size_t SMALL = 1ull << 20;
  unsigned short* wbf = (unsigned short*)(ws + SMALL);                  // 32 MiB
  unsigned short* xbf = (unsigned short*)(ws + SMALL + (32ull << 20));  // 64 MiB

  const bool haveX = ws_size >= SMALL + (96ull << 20);

  k_cwd<<<1, 256, 0, stream>>>(lnw, lnb, Wd, cL, cB);
  k_rows<<<2048, 256, 0, stream>>>(x, Am, lnw, Wd, cL, cB, t_ws, bk_ws, xbf, haveX ? 1 : 0);

  if (haveX){
    k_convert_bf16<<<16384, 256, 0, stream>>>(Wb, wbf, 4194304);
    k_gemm_pre<<<2048, 256, 0, stream>>>(xbf, wbf, bb, t_ws, bk_ws, Bl, Wu, al, out);
  } else {
    dim3 gg(32, 64);
    k_gemm_none<<<gg, 256, 0, stream>>>(x, Wb, bb, t_ws, bk_ws, Bl, Wu, al, out);
  }
}